// Round 19
// baseline (61.627 us; speedup 1.0000x reference)
//
#include <hip/hip_runtime.h>
#include <hip/hip_bf16.h>

#define L_SEQ 4096
#define NB 2
#define NH 8
#define DHEAD 64
#define DMODEL 512
#define MROWS 8192
#define NTILES 64
#define KWT 1   // band half-width in 64-key tiles; min excluded |i-j| = 65
                // worst-case far-field error ~2e-4 (R8 analysis), budget 1.96e-3

typedef __attribute__((ext_vector_type(8))) short bf16x8;
typedef __attribute__((ext_vector_type(4))) float f32x4;

#define LOG2_DECAY (-0.07400058144377693f)
#define LOG2E 1.4426950408889634f
#define C_SE (0.125f * LOG2E)        // scale * log2(e), folded into decay factors
#define C_M8 (-8.0f * LOG2E)         // -M0 * log2(e)
#define EM8 3.3546262790251185e-4f   // exp(-8)

__device__ __forceinline__ unsigned short f2b(float f) {
    __hip_bfloat16 h = __float2bfloat16(f);
    return *reinterpret_cast<unsigned short*>(&h);
}
__device__ __forceinline__ float b2f(unsigned short u) {
    unsigned int x = ((unsigned int)u) << 16;
    return *reinterpret_cast<float*>(&x);
}
// one-instruction packed f32->bf16 (RNE), same semantics as __float2bfloat16
__device__ __forceinline__ unsigned cvtpk_bf16(float lo, float hi) {
    unsigned r;
    asm("v_cvt_pk_bf16_f32 %0, %1, %2" : "=v"(r) : "v"(lo), "v"(hi));
    return r;
}
__device__ __forceinline__ unsigned short f2b_fast(float f) {
    return (unsigned short)(cvtpk_bf16(f, f) & 0xffffu);
}
__device__ __forceinline__ float fast_exp2(float x) {
    float r;
    asm("v_exp_f32 %0, %1" : "=v"(r) : "v"(x));
    return r;
}
__device__ __forceinline__ void load_lds16(const void* g, void* l) {
    __builtin_amdgcn_global_load_lds(
        (const __attribute__((address_space(1))) unsigned int*)g,
        (__attribute__((address_space(3))) unsigned int*)l, 16, 0, 0);
}

// weights-only bf16 cast (x is consumed as f32 directly by gemm_qkv)
__global__ void cast_w(const float* __restrict__ Wq, const float* __restrict__ Wk,
                       const float* __restrict__ Wv, const float* __restrict__ Wo,
                       unsigned short* __restrict__ wqb, unsigned short* __restrict__ wkb,
                       unsigned short* __restrict__ wvb, unsigned short* __restrict__ wob) {
    const int NW = DMODEL * DMODEL;
    int i4 = (blockIdx.x * blockDim.x + threadIdx.x) * 4;
    int w = i4 >> 18;               // NW = 2^18
    int off = i4 & (NW - 1);
    const float* s = w == 0 ? Wq : w == 1 ? Wk : w == 2 ? Wv : Wo;
    unsigned short* o = w == 0 ? wqb : w == 1 ? wkb : w == 2 ? wvb : wob;
    float4 v = *reinterpret_cast<const float4*>(s + off);
    unsigned lo = cvtpk_bf16(v.x, v.y);
    unsigned hi = cvtpk_bf16(v.z, v.w);
    *reinterpret_cast<uint2*>(o + off) = make_uint2(lo, hi);
}

// fused QKV projection (R15 structure): BM=128 BK=64, A reg-staged padded [128][72],
// W gload_lds source-XOR-swizzled. R19: A-prefetch DEPTH 2 (vaA/vaB) so X loads
// get ~2 compute phases to land before the A-write consumes them.
__global__ __launch_bounds__(256, 2) void gemm_qkv(const float* __restrict__ Xf,
                                                   const unsigned short* __restrict__ W0,
                                                   const unsigned short* __restrict__ W1,
                                                   const unsigned short* __restrict__ W2,
                                                   const float* __restrict__ b0,
                                                   const float* __restrict__ b1,
                                                   const float* __restrict__ b2,
                                                   unsigned short* __restrict__ oQ,
                                                   unsigned short* __restrict__ oK,
                                                   unsigned short* __restrict__ oV,
                                                   float* __restrict__ TS) {
    __shared__ __align__(64) unsigned char smem[43008];   // 18K A[128][72] + 24K W(q,k,v)
    unsigned short* As = (unsigned short*)smem;            // [128][72]
    const int tid = threadIdx.x;
    const int lane = tid & 63;
    const int wave = tid >> 6;
    const int r16 = lane & 15;
    const int g = lane >> 4;
    const int wr = wave >> 1, wc = wave & 1;
    const int m0 = blockIdx.x * 128;
    const int n0 = blockIdx.y * 64;

    const int arow = tid >> 3;          // 0..31
    const int acol = (tid & 7) * 8;     // 8-float segment
    const int wsw = (((lane & 7) ^ ((lane >> 3) & 7))) * 8;

    float4 vaA[4][2], vaB[4][2];
#define ISSUE_TO(VA, K0) { \
    _Pragma("unroll") \
    for (int j = 0; j < 4; ++j) { \
        const float* xp = Xf + (size_t)(m0 + arow + j * 32) * DMODEL + (K0) + acol; \
        VA[j][0] = *(const float4*)xp; \
        VA[j][1] = *(const float4*)(xp + 4); \
    } }

    f32x4 acc[3][4][2] = {};
    ISSUE_TO(vaA, 0);
    ISSUE_TO(vaB, 64);

#define QKV_STEP(S, VA) { \
    _Pragma("unroll") \
    for (int j = 0; j < 4; ++j) { \
        unsigned w0 = cvtpk_bf16(VA[j][0].x, VA[j][0].y); \
        unsigned w1 = cvtpk_bf16(VA[j][0].z, VA[j][0].w); \
        unsigned w2 = cvtpk_bf16(VA[j][1].x, VA[j][1].y); \
        unsigned w3 = cvtpk_bf16(VA[j][1].z, VA[j][1].w); \
        *reinterpret_cast<int4*>(As + (size_t)(arow + j * 32) * 72 + acol) = \
            make_int4(w0, w1, w2, w3); \
    } \
    _Pragma("unroll") \
    for (int c = 0; c < 6; ++c) { \
        int ch = wave * 6 + c; \
        int zz = ch >> 3; \
        int sub = ch & 7; \
        int row = sub * 8 + (lane >> 3); \
        const unsigned short* W = zz == 0 ? W0 : zz == 1 ? W1 : W2; \
        load_lds16(W + (size_t)(n0 + row) * DMODEL + (S) * 64 + wsw, \
                   smem + 18432 + zz * 8192 + sub * 1024); \
    } \
    __syncthreads(); \
    if ((S) + 2 < 8) ISSUE_TO(VA, ((S) + 2) * 64); \
    __builtin_amdgcn_s_setprio(1); \
    _Pragma("unroll") \
    for (int kk = 0; kk < 2; ++kk) { \
        bf16x8 a[4]; \
        _Pragma("unroll") \
        for (int i = 0; i < 4; ++i) \
            a[i] = *(const bf16x8*)(As + (wr * 64 + i * 16 + r16) * 72 + g * 8 + kk * 32); \
        _Pragma("unroll") \
        for (int zz = 0; zz < 3; ++zz) { \
            const unsigned short* Bs = (const unsigned short*)(smem + 18432 + zz * 8192); \
            _Pragma("unroll") \
            for (int j = 0; j < 2; ++j) { \
                int brow = wc * 32 + j * 16 + r16; \
                int bslot = ((g + kk * 4) ^ (r16 & 7)) * 8; \
                bf16x8 bfr = *(const bf16x8*)(Bs + brow * 64 + bslot); \
                _Pragma("unroll") \
                for (int i = 0; i < 4; ++i) \
                    acc[zz][i][j] = __builtin_amdgcn_mfma_f32_16x16x32_bf16(a[i], bfr, acc[zz][i][j], 0, 0, 0); \
            } \
        } \
    } \
    __builtin_amdgcn_s_setprio(0); \
    __syncthreads(); }

    for (int s2 = 0; s2 < 4; ++s2) {
        QKV_STEP(2 * s2, vaA);
        QKV_STEP(2 * s2 + 1, vaB);
    }
#undef QKV_STEP
#undef ISSUE_TO

    const int b = m0 >> 12;
    const int l0 = m0 & 4095;
    const int h = (n0 >> 6) & 7;

    // Q, K scatter epilogues (R9 config)
#pragma unroll
    for (int zz = 0; zz < 2; ++zz) {
        const float* bias = zz == 0 ? b0 : b1;
        unsigned short* outB = zz == 0 ? oQ : oK;
#pragma unroll
        for (int i = 0; i < 4; ++i)
#pragma unroll
            for (int j = 0; j < 2; ++j)
#pragma unroll
                for (int r = 0; r < 4; ++r) {
                    int m = m0 + wr * 64 + i * 16 + g * 4 + r;
                    int n = n0 + wc * 32 + j * 16 + r16;
                    float v = acc[zz][i][j][r] + bias[n];
                    int l = m & 4095, hd = n & 63;
                    outB[((size_t)(b * NH + h) * L_SEQ + l) * DHEAD + hd] = f2b_fast(v);
                }
    }

    // V: transpose through LDS -> [B,H,Hd,L] + per-tile sums TS
    __syncthreads();
    unsigned short* xsT = (unsigned short*)smem;  // [64][136] (17408B <= 18432B A region)
#pragma unroll
    for (int i = 0; i < 4; ++i)
#pragma unroll
        for (int j = 0; j < 2; ++j)
#pragma unroll
            for (int r = 0; r < 4; ++r) {
                int nl = wc * 32 + j * 16 + r16;
                int ml = wr * 64 + i * 16 + g * 4 + r;
                xsT[nl * 136 + ml] = f2b_fast(acc[2][i][j][r] + b2[n0 + nl]);
            }
    __syncthreads();
    {
        int drow = tid >> 2, part = tid & 3;
        size_t vb = ((size_t)((b * NH + h) * DHEAD + drow)) * L_SEQ + l0 + part * 32;
#pragma unroll
        for (int e = 0; e < 4; ++e)
            *reinterpret_cast<int4*>(oV + vb + e * 8) =
                *reinterpret_cast<const int4*>(&xsT[drow * 136 + part * 32 + e * 8]);
    }
    if (tid < 128) {
        int d = tid & 63, half = tid >> 6;
        float s = 0.f;
#pragma unroll
        for (int jj = 0; jj < 64; jj += 8) {
            bf16x8 v8 = *reinterpret_cast<const bf16x8*>(&xsT[d * 136 + half * 64 + jj]);
#pragma unroll
            for (int e = 0; e < 8; ++e) s += b2f((unsigned short)v8[e]);
        }
        TS[((size_t)(b * NH + h) * NTILES + (l0 >> 6) + half) * 64 + d] = s;
    }
}

// output projection: BM=64, both tiles gload_lds with source XOR-swizzle (fp32 out)
__global__ __launch_bounds__(256) void gemm_out(const unsigned short* __restrict__ X,
                                                const unsigned short* __restrict__ W,
                                                const float* __restrict__ bias,
                                                float* __restrict__ outF) {
    __shared__ __align__(64) unsigned char smem[16384];   // 8K A + 8K W
    unsigned short* As = (unsigned short*)smem;            // [64][64] row-XOR layout
    unsigned short* Bs = (unsigned short*)(smem + 8192);   // [64][64] row-XOR layout
    const int tid = threadIdx.x;
    const int lane = tid & 63;
    const int wave = tid >> 6;
    const int r16 = lane & 15;
    const int g = lane >> 4;
    const int wr = wave >> 1, wc = wave & 1;
    const int m0 = blockIdx.x * 64;
    const int n0 = blockIdx.y * 64;
    const int wsw = (((lane & 7) ^ ((lane >> 3) & 7))) * 8;

    f32x4 acc[2][2] = {};
    for (int k0 = 0; k0 < DMODEL; k0 += 64) {
        __syncthreads();
#pragma unroll
        for (int c = 0; c < 4; ++c) {
            int ch = wave * 4 + c;
            const unsigned short* gp;
            unsigned char* lp;
            if (ch < 8) {
                int row = ch * 8 + (lane >> 3);
                gp = X + (size_t)(m0 + row) * DMODEL + k0 + wsw;
                lp = smem + ch * 1024;
            } else {
                int row = (ch - 8) * 8 + (lane >> 3);
                gp = W + (size_t)(n0 + row) * DMODEL + k0 + wsw;
                lp = smem + 8192 + (ch - 8) * 1024;
            }
            load_lds16(gp, lp);
        }
        __syncthreads();
#pragma unroll
        for (int kk = 0; kk < 2; ++kk) {
            int slot = ((g + kk * 4) ^ (r16 & 7)) * 8;
            bf16x8 bfr[2];
#pragma unroll
            for (int j = 0; j < 2; ++j)
                bfr[j] = *(const bf16x8*)(Bs + (wc * 32 + j * 16 + r16) * 64 + slot);
#pragma unroll
            for (int i = 0; i < 2; ++i) {
                bf16x8 a = *(const bf16x8*)(As + (wr * 32 + i * 16 + r16) * 64 + slot);
#pragma unroll
                for (int j = 0; j < 2; ++j)
                    acc[i][j] = __builtin_amdgcn_mfma_f32_16x16x32_bf16(a, bfr[j], acc[i][j], 0, 0, 0);
            }
        }
    }
#pragma unroll
    for (int i = 0; i < 2; ++i)
#pragma unroll
        for (int j = 0; j < 2; ++j)
#pragma unroll
            for (int r = 0; r < 4; ++r) {
                int m = m0 + wr * 32 + i * 16 + g * 4 + r;
                int n = n0 + wc * 32 + j * 16 + r16;
                outF[(size_t)m * DMODEL + n] = acc[i][j][r] + bias[n];
            }
}

// attention: QBLK=128, double-buffered K/V LDS -> ONE barrier per k-tile (R18).
__global__ __launch_bounds__(256) void attn_fused(const unsigned short* __restrict__ Qg,
                                                  const unsigned short* __restrict__ Kg,
                                                  const unsigned short* __restrict__ Vtg,
                                                  const float* __restrict__ TS,
                                                  unsigned short* __restrict__ Og) {
    __shared__ __align__(16) unsigned short ks[2][64][72];
    __shared__ __align__(16) unsigned short vt[2][64][72];
    __shared__ __align__(16) unsigned short ps[4][32][72];
    __shared__ float Fp[4][64];
    __shared__ float Ftot[64];
    __shared__ float Fband[2][64];
    const int tid = threadIdx.x;
    const int lane = tid & 63;
    const int wave = tid >> 6;
    const int r16 = lane & 15;
    const int g = lane >> 4;
    const int bh = blockIdx.y;
    const int qb = blockIdx.x;
    const int q0 = qb * 128;
    const int qt0 = qb * 2, qt1 = qt0 + 1;
    const size_t base = (size_t)bh * L_SEQ * DHEAD;
    const unsigned short* Qb = Qg + base;
    const unsigned short* Kb = Kg + base;
    const unsigned short* Vtb = Vtg + base;

    const int qtw = qt0 + (wave >> 1);                     // this wave's q-tile
    const int t_lo_w = (qtw - KWT) > 0 ? (qtw - KWT) : 0;
    const int t_hi_w = (qtw + KWT + 1) < NTILES ? (qtw + KWT + 1) : NTILES;
    const int t_lo_u = (qt0 - KWT) > 0 ? (qt0 - KWT) : 0;
    const int t_hi_u = (qt1 + KWT + 1) < NTILES ? (qt1 + KWT + 1) : NTILES;

    // first K/V prefetch
    const int srow = tid >> 2;
    const int scol = (tid & 3) * 16;
    int4 kr0, kr1, vr0, vr1;
#define ISSUE(KT) { \
    const unsigned short* kp = Kb + ((size_t)((KT) * 64 + srow)) * DHEAD + scol; \
    kr0 = *(const int4*)kp; kr1 = *(const int4*)(kp + 8); \
    const unsigned short* vp = Vtb + (size_t)srow * L_SEQ + (KT) * 64 + scol; \
    vr0 = *(const int4*)vp; vr1 = *(const int4*)(vp + 8); }
    ISSUE(t_lo_u);

    // Q fragments: 2 per wave (rows q0 + wave*32 + f*16 + r16)
    bf16x8 qa[2][2];
#pragma unroll
    for (int f = 0; f < 2; ++f) {
        const unsigned short* qp = Qb + (size_t)(q0 + wave * 32 + f * 16 + r16) * DHEAD + 8 * g;
        qa[f][0] = *reinterpret_cast<const bf16x8*>(qp);
        qa[f][1] = *reinterpret_cast<const bf16x8*>(qp + 32);
    }

    // far-field V sums (hoisted: TS loads overlap the K/V/Q prefetch latency)
    const float* tsb = TS + (size_t)bh * NTILES * 64;
    {
        int d = tid & 63, c = tid >> 6;
        float f = 0.f;
        for (int t = c; t < NTILES; t += 4) f += tsb[t * 64 + d];
        Fp[c][d] = f;
    }
    __syncthreads();
    if (tid < 64) Ftot[tid] = Fp[0][tid] + Fp[1][tid] + Fp[2][tid] + Fp[3][tid];
    if (tid < 128) {
        int d = tid & 63, which = tid >> 6;
        int qt = which ? qt1 : qt0;
        int tl = (qt - KWT) > 0 ? (qt - KWT) : 0;
        int th = (qt + KWT + 1) < NTILES ? (qt + KWT + 1) : NTILES;
        float s = 0.f;
        for (int t = tl; t < th; ++t) s += tsb[t * 64 + d];
        Fband[which][d] = s;
    }
    // Ftot/Fband visible to all after the loop's first __syncthreads

    // decay factorization (C_SE folded): mask_se = min(s0f*rowf*colfI, s0b*rowfI*colf)
    float rowf[2][4], rowfI[2][4], colf[4], colfI[4];
#pragma unroll
    for (int f = 0; f < 2; ++f)
#pragma unroll
        for (int r = 0; r < 4; ++r) {
            float dq = (float)(wave * 32 + f * 16 + g * 4 + r);
            rowf[f][r] = fast_exp2(dq * LOG2_DECAY);
            rowfI[f][r] = fast_exp2(-dq * LOG2_DECAY);
        }
#pragma unroll
    for (int t = 0; t < 4; ++t) {
        float dk = (float)(t * 16 + r16);
        colf[t] = fast_exp2(dk * LOG2_DECAY);
        colfI[t] = fast_exp2(-dk * LOG2_DECAY);
    }
    float s0f = C_SE * fast_exp2((float)(q0 - 64 * t_lo_u) * LOG2_DECAY);
    float s0b = C_SE * fast_exp2(-(float)(q0 - 64 * t_lo_u) * LOG2_DECAY);
    const float stepF = fast_exp2(-64.f * LOG2_DECAY);
    const float stepB = fast_exp2(64.f * LOG2_DECAY);

    f32x4 acc[2][4] = {};
    float lpart[2][4] = {};
    int p = 0;

    for (int kt = t_lo_u; kt < t_hi_u; ++kt) {
        // stage current tile into buf[p] from registers (prev iteration's prefetch)
        *(int4*)&ks[p][srow][scol] = kr0;
        *(int4*)&ks[p][srow][scol + 8] = kr1;
        *(int4*)&vt[p][srow][scol] = vr0;
        *(int4*)&vt[p][srow][scol + 8] = vr1;
        __syncthreads();                       // buf[p] visible; prior reads of buf[p] done
        if (kt + 1 < t_hi_u) ISSUE(kt + 1);    // prefetch flies during compute

        if (kt >= t_lo_w && kt < t_hi_w) {     // wave-uniform band check
            f32x4 sc[2][4];
            __builtin_amdgcn_s_setprio(1);
#pragma unroll
            for (int t = 0; t < 4; ++t) {
                bf16x8 b0 = *reinterpret_cast<const bf16x8*>(&ks[p][t * 16 + r16][8 * g]);
                bf16x8 b1 = *reinterpret_cast<const bf16x8*>(&ks[p][t * 16 + r16][8 * g + 32]);
#pragma unroll
                for (int f = 0; f < 2; ++f) {
                    f32x4 z = {};
                    z = __builtin_amdgcn_mfma_f32_16x16x32_bf16(qa[f][0], b0, z, 0, 0, 0);
                    z = __builtin_amdgcn_mfma_f32_16x16x32_bf16(qa[f][1], b1, z, 0, 0, 0);
                    sc[f][t] = z;
                }
            }
            __builtin_amdgcn_s_setprio(0);

#pragma unroll
            for (int f = 0; f < 2; ++f) {
                float faf[4], fab[4];
#pragma unroll
                for (int r = 0; r < 4; ++r) {
                    faf[r] = s0f * rowf[f][r];
                    fab[r] = s0b * rowfI[f][r];
                }
#pragma unroll
                for (int t = 0; t < 4; ++t) {
#pragma unroll
                    for (int r = 0; r < 4; ++r) {
                        float mask_se = fminf(faf[r] * colfI[t], fab[r] * colf[t]);
                        float p_ = fast_exp2(fmaf(sc[f][t][r], mask_se, C_M8));
                        lpart[f][r] += p_;
                        ps[wave][f * 16 + g * 4 + r][t * 16 + r16] = f2b_fast(p_);
                    }
                }
            }
            // ps is wave-private; same-wave LDS ordering suffices (proven R2-R18)
            __builtin_amdgcn_s_setprio(1);
#pragma unroll
            for (int f = 0; f < 2; ++f)
#pragma unroll
                for (int t = 0; t < 4; ++t) {
#pragma unroll
                    for (int kk0 = 0; kk0 < 64; kk0 += 32) {
                        bf16x8 pa = *reinterpret_cast<const bf16x8*>(&ps[wave][f * 16 + r16][8 * g + kk0]);
                        bf16x8 vb = *reinterpret_cast<const bf16x8*>(&vt[p][t * 16 + r16][8 * g + kk0]);
                        acc[f][t] = __builtin_amdgcn_mfma_f32_16x16x32_bf16(pa, vb, acc[f][t], 0, 0, 0);
                    }
                }
            __builtin_amdgcn_s_setprio(0);
        }
        s0f *= stepF;   // unconditional: keeps all waves' bases in sync
        s0b *= stepB;
        p ^= 1;         // next tile writes the other buffer (no trailing barrier)
    }
#undef ISSUE

#pragma unroll
    for (int f = 0; f < 2; ++f)
#pragma unroll
        for (int r = 0; r < 4; ++r) {
#pragma unroll
            for (int sh = 1; sh < 16; sh <<= 1)
                lpart[f][r] += __shfl_xor(lpart[f][r], sh);
        }

    const int whichw = wave >> 1;
    const int nfar = L_SEQ - 64 * (t_hi_w - t_lo_w);
    const int b = bh >> 3, h = bh & 7;
#pragma unroll
    for (int f = 0; f < 2; ++f) {
        float inv[4];
#pragma unroll
        for (int r = 0; r < 4; ++r)
            inv[r] = 1.0f / (lpart[f][r] + EM8 * (float)nfar);
#pragma unroll
        for (int t = 0; t < 4; ++t) {
            float F = Ftot[t * 16 + r16] - Fband[whichw][t * 16 + r16];
#pragma unroll
            for (int r = 0; r < 4; ++r) {
                int row = q0 + wave * 32 + f * 16 + g * 4 + r;
                float o = (acc[f][t][r] + EM8 * F) * inv[r];
                Og[((size_t)(b * L_SEQ) + row) * DMODEL + h * DHEAD + t * 16 + r16] = f2b_fast(o);
            }
        }
    }
}

extern "C" void kernel_launch(void* const* d_in, const int* in_sizes, int n_in,
                              void* d_out, int out_size, void* d_ws, size_t ws_size,
                              hipStream_t stream) {
    const float* x  = (const float*)d_in[0];
    const float* Wq = (const float*)d_in[1];
    const float* bq = (const float*)d_in[2];
    const float* Wk = (const float*)d_in[3];
    const float* bk = (const float*)d_in[4];
    const float* Wv = (const float*)d_in[5];
    const float* bv = (const float*)d_in[6];
    const float* Wo = (const float*)d_in[7];
    const float* bo = (const float*)d_in[8];
    float* out = (float*)d_out;

    const int NX = MROWS * DMODEL;
    const int NW = DMODEL * DMODEL;

    unsigned short* aout = (unsigned short*)d_ws;  // attn output (bf16)
    unsigned short* wqb = aout + NX;
    unsigned short* wkb = wqb + NW;
    unsigned short* wvb = wkb + NW;
    unsigned short* wob = wvb + NW;
    unsigned short* qws = wob + NW;
    unsigned short* kws = qws + NX;
    unsigned short* vtg = kws + NX;                // V transposed [B,H,Hd,L]
    float* TS = (float*)(vtg + NX);

    cast_w<<<(4 * NW / 4) / 256, 256, 0, stream>>>(Wq, Wk, Wv, Wo, wqb, wkb, wvb, wob);

    dim3 gq(MROWS / 128, DMODEL / 64);
    gemm_qkv<<<gq, 256, 0, stream>>>(x, wqb, wkb, wvb, bq, bk, bv, qws, kws, vtg, TS);

    dim3 ga(L_SEQ / 128, NB * NH);
    attn_fused<<<ga, 256, 0, stream>>>(qws, kws, vtg, TS, aout);

    dim3 go(MROWS / 64, DMODEL / 64);
    gemm_out<<<go, 256, 0, stream>>>(aout, wob, bo, out);
}

// Round 20
// 59.613 us; speedup vs baseline: 1.0338x; 1.0338x over previous
//
#include <hip/hip_runtime.h>
#include <hip/hip_bf16.h>

#define L_SEQ 4096
#define NB 2
#define NH 8
#define DHEAD 64
#define DMODEL 512
#define MROWS 8192
#define NTILES 64
#define KWT 1   // band half-width in 64-key tiles; min excluded |i-j| = 65
                // worst-case far-field error ~2e-4 (R8 analysis), budget 1.96e-3

typedef __attribute__((ext_vector_type(8))) short bf16x8;
typedef __attribute__((ext_vector_type(4))) float f32x4;

#define LOG2_DECAY (-0.07400058144377693f)
#define LOG2E 1.4426950408889634f
#define C_SE (0.125f * LOG2E)        // scale * log2(e), folded into decay factors
#define C_M8 (-8.0f * LOG2E)         // -M0 * log2(e)
#define EM8 3.3546262790251185e-4f   // exp(-8)

__device__ __forceinline__ unsigned short f2b(float f) {
    __hip_bfloat16 h = __float2bfloat16(f);
    return *reinterpret_cast<unsigned short*>(&h);
}
__device__ __forceinline__ float b2f(unsigned short u) {
    unsigned int x = ((unsigned int)u) << 16;
    return *reinterpret_cast<float*>(&x);
}
// one-instruction packed f32->bf16 (RNE), same semantics as __float2bfloat16
__device__ __forceinline__ unsigned cvtpk_bf16(float lo, float hi) {
    unsigned r;
    asm("v_cvt_pk_bf16_f32 %0, %1, %2" : "=v"(r) : "v"(lo), "v"(hi));
    return r;
}
__device__ __forceinline__ unsigned short f2b_fast(float f) {
    return (unsigned short)(cvtpk_bf16(f, f) & 0xffffu);
}
__device__ __forceinline__ float fast_exp2(float x) {
    float r;
    asm("v_exp_f32 %0, %1" : "=v"(r) : "v"(x));
    return r;
}
__device__ __forceinline__ void load_lds16(const void* g, void* l) {
    __builtin_amdgcn_global_load_lds(
        (const __attribute__((address_space(1))) unsigned int*)g,
        (__attribute__((address_space(3))) unsigned int*)l, 16, 0, 0);
}

// weights-only bf16 cast (x is consumed as f32 directly by gemm_qkv)
__global__ void cast_w(const float* __restrict__ Wq, const float* __restrict__ Wk,
                       const float* __restrict__ Wv, const float* __restrict__ Wo,
                       unsigned short* __restrict__ wqb, unsigned short* __restrict__ wkb,
                       unsigned short* __restrict__ wvb, unsigned short* __restrict__ wob) {
    const int NW = DMODEL * DMODEL;
    int i4 = (blockIdx.x * blockDim.x + threadIdx.x) * 4;
    int w = i4 >> 18;               // NW = 2^18
    int off = i4 & (NW - 1);
    const float* s = w == 0 ? Wq : w == 1 ? Wk : w == 2 ? Wv : Wo;
    unsigned short* o = w == 0 ? wqb : w == 1 ? wkb : w == 2 ? wvb : wob;
    float4 v = *reinterpret_cast<const float4*>(s + off);
    unsigned lo = cvtpk_bf16(v.x, v.y);
    unsigned hi = cvtpk_bf16(v.z, v.w);
    *reinterpret_cast<uint2*>(o + off) = make_uint2(lo, hi);
}

// fused QKV projection (R15/R18 champion, byte-identical): BM=128 BK=64,
// A reg-staged padded [128][72]; W gload_lds source-XOR-swizzled.
__global__ __launch_bounds__(256, 2) void gemm_qkv(const float* __restrict__ Xf,
                                                   const unsigned short* __restrict__ W0,
                                                   const unsigned short* __restrict__ W1,
                                                   const unsigned short* __restrict__ W2,
                                                   const float* __restrict__ b0,
                                                   const float* __restrict__ b1,
                                                   const float* __restrict__ b2,
                                                   unsigned short* __restrict__ oQ,
                                                   unsigned short* __restrict__ oK,
                                                   unsigned short* __restrict__ oV,
                                                   float* __restrict__ TS) {
    __shared__ __align__(64) unsigned char smem[43008];   // 18K A[128][72] + 24K W(q,k,v)
    unsigned short* As = (unsigned short*)smem;            // [128][72]
    const int tid = threadIdx.x;
    const int lane = tid & 63;
    const int wave = tid >> 6;
    const int r16 = lane & 15;
    const int g = lane >> 4;
    const int wr = wave >> 1, wc = wave & 1;
    const int m0 = blockIdx.x * 128;
    const int n0 = blockIdx.y * 64;

    const int arow = tid >> 3;          // 0..31
    const int acol = (tid & 7) * 8;     // 8-float segment
    // W source pre-swizzle: lane fetches col-slot (lane&7)^((lane>>3)&7) so the
    // linear gload_lds dest realizes a row-XOR layout (read: slot (g+4kk)^(row&7))
    const int wsw = (((lane & 7) ^ ((lane >> 3) & 7))) * 8;

    float4 va[4][2];
#define ISSUE_A(K0) { \
    _Pragma("unroll") \
    for (int j = 0; j < 4; ++j) { \
        const float* xp = Xf + (size_t)(m0 + arow + j * 32) * DMODEL + (K0) + acol; \
        va[j][0] = *(const float4*)xp; \
        va[j][1] = *(const float4*)(xp + 4); \
    } }

    f32x4 acc[3][4][2] = {};
    ISSUE_A(0);
    for (int s = 0; s < 8; ++s) {
        // write A (cvt f32->bf16) into padded [128][72]; 2-way bank pattern (free)
#pragma unroll
        for (int j = 0; j < 4; ++j) {
            unsigned w0 = cvtpk_bf16(va[j][0].x, va[j][0].y);
            unsigned w1 = cvtpk_bf16(va[j][0].z, va[j][0].w);
            unsigned w2 = cvtpk_bf16(va[j][1].x, va[j][1].y);
            unsigned w3 = cvtpk_bf16(va[j][1].z, va[j][1].w);
            *reinterpret_cast<int4*>(As + (size_t)(arow + j * 32) * 72 + acol) =
                make_int4(w0, w1, w2, w3);
        }
        // stage the three W tiles via gload_lds with pre-swizzled global source
#pragma unroll
        for (int c = 0; c < 6; ++c) {
            int ch = wave * 6 + c;
            int zz = ch >> 3;
            int sub = ch & 7;
            int row = sub * 8 + (lane >> 3);
            const unsigned short* W = zz == 0 ? W0 : zz == 1 ? W1 : W2;
            load_lds16(W + (size_t)(n0 + row) * DMODEL + s * 64 + wsw,
                       smem + 18432 + zz * 8192 + sub * 1024);
        }
        __syncthreads();                  // drains vmcnt+lgkmcnt: tile ready
        if (s < 7) ISSUE_A((s + 1) * 64); // next A flies during compute
        __builtin_amdgcn_s_setprio(1);
#pragma unroll
        for (int kk = 0; kk < 2; ++kk) {
            bf16x8 a[4];
#pragma unroll
            for (int i = 0; i < 4; ++i)
                a[i] = *(const bf16x8*)(As + (wr * 64 + i * 16 + r16) * 72 + g * 8 + kk * 32);
#pragma unroll
            for (int zz = 0; zz < 3; ++zz) {
                const unsigned short* Bs = (const unsigned short*)(smem + 18432 + zz * 8192);
#pragma unroll
                for (int j = 0; j < 2; ++j) {
                    int brow = wc * 32 + j * 16 + r16;
                    int bslot = ((g + kk * 4) ^ (r16 & 7)) * 8;
                    bf16x8 bfr = *(const bf16x8*)(Bs + brow * 64 + bslot);
#pragma unroll
                    for (int i = 0; i < 4; ++i)
                        acc[zz][i][j] = __builtin_amdgcn_mfma_f32_16x16x32_bf16(a[i], bfr, acc[zz][i][j], 0, 0, 0);
                }
            }
        }
        __builtin_amdgcn_s_setprio(0);
        __syncthreads();                  // all reads of tile done before overwrite
    }
#undef ISSUE_A

    const int b = m0 >> 12;
    const int l0 = m0 & 4095;
    const int h = (n0 >> 6) & 7;

    // Q, K scatter epilogues (R9 config)
#pragma unroll
    for (int zz = 0; zz < 2; ++zz) {
        const float* bias = zz == 0 ? b0 : b1;
        unsigned short* outB = zz == 0 ? oQ : oK;
#pragma unroll
        for (int i = 0; i < 4; ++i)
#pragma unroll
            for (int j = 0; j < 2; ++j)
#pragma unroll
                for (int r = 0; r < 4; ++r) {
                    int m = m0 + wr * 64 + i * 16 + g * 4 + r;
                    int n = n0 + wc * 32 + j * 16 + r16;
                    float v = acc[zz][i][j][r] + bias[n];
                    int l = m & 4095, hd = n & 63;
                    outB[((size_t)(b * NH + h) * L_SEQ + l) * DHEAD + hd] = f2b_fast(v);
                }
    }

    // V: transpose through LDS -> [B,H,Hd,L] + per-tile sums TS
    __syncthreads();
    unsigned short* xsT = (unsigned short*)smem;  // [64][136] (17408B <= 18432B A region)
#pragma unroll
    for (int i = 0; i < 4; ++i)
#pragma unroll
        for (int j = 0; j < 2; ++j)
#pragma unroll
            for (int r = 0; r < 4; ++r) {
                int nl = wc * 32 + j * 16 + r16;
                int ml = wr * 64 + i * 16 + g * 4 + r;
                xsT[nl * 136 + ml] = f2b_fast(acc[2][i][j][r] + b2[n0 + nl]);
            }
    __syncthreads();
    {
        int drow = tid >> 2, part = tid & 3;
        size_t vb = ((size_t)((b * NH + h) * DHEAD + drow)) * L_SEQ + l0 + part * 32;
#pragma unroll
        for (int e = 0; e < 4; ++e)
            *reinterpret_cast<int4*>(oV + vb + e * 8) =
                *reinterpret_cast<const int4*>(&xsT[drow * 136 + part * 32 + e * 8]);
    }
    if (tid < 128) {
        int d = tid & 63, half = tid >> 6;
        float s = 0.f;
#pragma unroll
        for (int jj = 0; jj < 64; jj += 8) {
            bf16x8 v8 = *reinterpret_cast<const bf16x8*>(&xsT[d * 136 + half * 64 + jj]);
#pragma unroll
            for (int e = 0; e < 8; ++e) s += b2f((unsigned short)v8[e]);
        }
        TS[((size_t)(b * NH + h) * NTILES + (l0 >> 6) + half) * 64 + d] = s;
    }
}

// output projection: BM=64, both tiles gload_lds with source XOR-swizzle (fp32 out)
__global__ __launch_bounds__(256) void gemm_out(const unsigned short* __restrict__ X,
                                                const unsigned short* __restrict__ W,
                                                const float* __restrict__ bias,
                                                float* __restrict__ outF) {
    __shared__ __align__(64) unsigned char smem[16384];   // 8K A + 8K W
    unsigned short* As = (unsigned short*)smem;            // [64][64] row-XOR layout
    unsigned short* Bs = (unsigned short*)(smem + 8192);   // [64][64] row-XOR layout
    const int tid = threadIdx.x;
    const int lane = tid & 63;
    const int wave = tid >> 6;
    const int r16 = lane & 15;
    const int g = lane >> 4;
    const int wr = wave >> 1, wc = wave & 1;
    const int m0 = blockIdx.x * 64;
    const int n0 = blockIdx.y * 64;
    const int wsw = (((lane & 7) ^ ((lane >> 3) & 7))) * 8;

    f32x4 acc[2][2] = {};
    for (int k0 = 0; k0 < DMODEL; k0 += 64) {
        __syncthreads();
#pragma unroll
        for (int c = 0; c < 4; ++c) {
            int ch = wave * 4 + c;
            const unsigned short* gp;
            unsigned char* lp;
            if (ch < 8) {
                int row = ch * 8 + (lane >> 3);
                gp = X + (size_t)(m0 + row) * DMODEL + k0 + wsw;
                lp = smem + ch * 1024;
            } else {
                int row = (ch - 8) * 8 + (lane >> 3);
                gp = W + (size_t)(n0 + row) * DMODEL + k0 + wsw;
                lp = smem + 8192 + (ch - 8) * 1024;
            }
            load_lds16(gp, lp);
        }
        __syncthreads();
#pragma unroll
        for (int kk = 0; kk < 2; ++kk) {
            int slot = ((g + kk * 4) ^ (r16 & 7)) * 8;
            bf16x8 bfr[2];
#pragma unroll
            for (int j = 0; j < 2; ++j)
                bfr[j] = *(const bf16x8*)(Bs + (wc * 32 + j * 16 + r16) * 64 + slot);
#pragma unroll
            for (int i = 0; i < 2; ++i) {
                bf16x8 a = *(const bf16x8*)(As + (wr * 32 + i * 16 + r16) * 64 + slot);
#pragma unroll
                for (int j = 0; j < 2; ++j)
                    acc[i][j] = __builtin_amdgcn_mfma_f32_16x16x32_bf16(a, bfr[j], acc[i][j], 0, 0, 0);
            }
        }
    }
#pragma unroll
    for (int i = 0; i < 2; ++i)
#pragma unroll
        for (int j = 0; j < 2; ++j)
#pragma unroll
            for (int r = 0; r < 4; ++r) {
                int m = m0 + wr * 32 + i * 16 + g * 4 + r;
                int n = n0 + wc * 32 + j * 16 + r16;
                outF[(size_t)m * DMODEL + n] = acc[i][j][r] + bias[n];
            }
}

// attention: QBLK=128, double-buffered K/V LDS -> ONE barrier per k-tile (R18).
__global__ __launch_bounds__(256) void attn_fused(const unsigned short* __restrict__ Qg,
                                                  const unsigned short* __restrict__ Kg,
                                                  const unsigned short* __restrict__ Vtg,
                                                  const float* __restrict__ TS,
                                                  unsigned short* __restrict__ Og) {
    __shared__ __align__(16) unsigned short ks[2][64][72];
    __shared__ __align__(16) unsigned short vt[2][64][72];
    __shared__ __align__(16) unsigned short ps[4][32][72];
    __shared__ float Fp[4][64];
    __shared__ float Ftot[64];
    __shared__ float Fband[2][64];
    const int tid = threadIdx.x;
    const int lane = tid & 63;
    const int wave = tid >> 6;
    const int r16 = lane & 15;
    const int g = lane >> 4;
    const int bh = blockIdx.y;
    const int qb = blockIdx.x;
    const int q0 = qb * 128;
    const int qt0 = qb * 2, qt1 = qt0 + 1;
    const size_t base = (size_t)bh * L_SEQ * DHEAD;
    const unsigned short* Qb = Qg + base;
    const unsigned short* Kb = Kg + base;
    const unsigned short* Vtb = Vtg + base;

    const int qtw = qt0 + (wave >> 1);                     // this wave's q-tile
    const int t_lo_w = (qtw - KWT) > 0 ? (qtw - KWT) : 0;
    const int t_hi_w = (qtw + KWT + 1) < NTILES ? (qtw + KWT + 1) : NTILES;
    const int t_lo_u = (qt0 - KWT) > 0 ? (qt0 - KWT) : 0;
    const int t_hi_u = (qt1 + KWT + 1) < NTILES ? (qt1 + KWT + 1) : NTILES;

    // first K/V prefetch
    const int srow = tid >> 2;
    const int scol = (tid & 3) * 16;
    int4 kr0, kr1, vr0, vr1;
#define ISSUE(KT) { \
    const unsigned short* kp = Kb + ((size_t)((KT) * 64 + srow)) * DHEAD + scol; \
    kr0 = *(const int4*)kp; kr1 = *(const int4*)(kp + 8); \
    const unsigned short* vp = Vtb + (size_t)srow * L_SEQ + (KT) * 64 + scol; \
    vr0 = *(const int4*)vp; vr1 = *(const int4*)(vp + 8); }
    ISSUE(t_lo_u);

    // Q fragments: 2 per wave (rows q0 + wave*32 + f*16 + r16)
    bf16x8 qa[2][2];
#pragma unroll
    for (int f = 0; f < 2; ++f) {
        const unsigned short* qp = Qb + (size_t)(q0 + wave * 32 + f * 16 + r16) * DHEAD + 8 * g;
        qa[f][0] = *reinterpret_cast<const bf16x8*>(qp);
        qa[f][1] = *reinterpret_cast<const bf16x8*>(qp + 32);
    }

    // far-field V sums (hoisted: TS loads overlap the K/V/Q prefetch latency)
    const float* tsb = TS + (size_t)bh * NTILES * 64;
    {
        int d = tid & 63, c = tid >> 6;
        float f = 0.f;
        for (int t = c; t < NTILES; t += 4) f += tsb[t * 64 + d];
        Fp[c][d] = f;
    }
    __syncthreads();
    if (tid < 64) Ftot[tid] = Fp[0][tid] + Fp[1][tid] + Fp[2][tid] + Fp[3][tid];
    if (tid < 128) {
        int d = tid & 63, which = tid >> 6;
        int qt = which ? qt1 : qt0;
        int tl = (qt - KWT) > 0 ? (qt - KWT) : 0;
        int th = (qt + KWT + 1) < NTILES ? (qt + KWT + 1) : NTILES;
        float s = 0.f;
        for (int t = tl; t < th; ++t) s += tsb[t * 64 + d];
        Fband[which][d] = s;
    }
    // Ftot/Fband visible to all after the loop's first __syncthreads

    // decay factorization (C_SE folded): mask_se = min(s0f*rowf*colfI, s0b*rowfI*colf)
    float rowf[2][4], rowfI[2][4], colf[4], colfI[4];
#pragma unroll
    for (int f = 0; f < 2; ++f)
#pragma unroll
        for (int r = 0; r < 4; ++r) {
            float dq = (float)(wave * 32 + f * 16 + g * 4 + r);
            rowf[f][r] = fast_exp2(dq * LOG2_DECAY);
            rowfI[f][r] = fast_exp2(-dq * LOG2_DECAY);
        }
#pragma unroll
    for (int t = 0; t < 4; ++t) {
        float dk = (float)(t * 16 + r16);
        colf[t] = fast_exp2(dk * LOG2_DECAY);
        colfI[t] = fast_exp2(-dk * LOG2_DECAY);
    }
    float s0f = C_SE * fast_exp2((float)(q0 - 64 * t_lo_u) * LOG2_DECAY);
    float s0b = C_SE * fast_exp2(-(float)(q0 - 64 * t_lo_u) * LOG2_DECAY);
    const float stepF = fast_exp2(-64.f * LOG2_DECAY);
    const float stepB = fast_exp2(64.f * LOG2_DECAY);

    f32x4 acc[2][4] = {};
    float lpart[2][4] = {};
    int p = 0;

    for (int kt = t_lo_u; kt < t_hi_u; ++kt) {
        // stage current tile into buf[p] from registers (prev iteration's prefetch)
        *(int4*)&ks[p][srow][scol] = kr0;
        *(int4*)&ks[p][srow][scol + 8] = kr1;
        *(int4*)&vt[p][srow][scol] = vr0;
        *(int4*)&vt[p][srow][scol + 8] = vr1;
        __syncthreads();                       // buf[p] visible; prior reads of buf[p] done
        if (kt + 1 < t_hi_u) ISSUE(kt + 1);    // prefetch flies during compute

        if (kt >= t_lo_w && kt < t_hi_w) {     // wave-uniform band check
            f32x4 sc[2][4];
            __builtin_amdgcn_s_setprio(1);
#pragma unroll
            for (int t = 0; t < 4; ++t) {
                bf16x8 b0 = *reinterpret_cast<const bf16x8*>(&ks[p][t * 16 + r16][8 * g]);
                bf16x8 b1 = *reinterpret_cast<const bf16x8*>(&ks[p][t * 16 + r16][8 * g + 32]);
#pragma unroll
                for (int f = 0; f < 2; ++f) {
                    f32x4 z = {};
                    z = __builtin_amdgcn_mfma_f32_16x16x32_bf16(qa[f][0], b0, z, 0, 0, 0);
                    z = __builtin_amdgcn_mfma_f32_16x16x32_bf16(qa[f][1], b1, z, 0, 0, 0);
                    sc[f][t] = z;
                }
            }
            __builtin_amdgcn_s_setprio(0);

#pragma unroll
            for (int f = 0; f < 2; ++f) {
                float faf[4], fab[4];
#pragma unroll
                for (int r = 0; r < 4; ++r) {
                    faf[r] = s0f * rowf[f][r];
                    fab[r] = s0b * rowfI[f][r];
                }
#pragma unroll
                for (int t = 0; t < 4; ++t) {
#pragma unroll
                    for (int r = 0; r < 4; ++r) {
                        float mask_se = fminf(faf[r] * colfI[t], fab[r] * colf[t]);
                        float p_ = fast_exp2(fmaf(sc[f][t][r], mask_se, C_M8));
                        lpart[f][r] += p_;
                        ps[wave][f * 16 + g * 4 + r][t * 16 + r16] = f2b_fast(p_);
                    }
                }
            }
            // ps is wave-private; same-wave LDS ordering suffices (proven R2-R18)
            __builtin_amdgcn_s_setprio(1);
#pragma unroll
            for (int f = 0; f < 2; ++f)
#pragma unroll
                for (int t = 0; t < 4; ++t) {
#pragma unroll
                    for (int kk0 = 0; kk0 < 64; kk0 += 32) {
                        bf16x8 pa = *reinterpret_cast<const bf16x8*>(&ps[wave][f * 16 + r16][8 * g + kk0]);
                        bf16x8 vb = *reinterpret_cast<const bf16x8*>(&vt[p][t * 16 + r16][8 * g + kk0]);
                        acc[f][t] = __builtin_amdgcn_mfma_f32_16x16x32_bf16(pa, vb, acc[f][t], 0, 0, 0);
                    }
                }
            __builtin_amdgcn_s_setprio(0);
        }
        s0f *= stepF;   // unconditional: keeps all waves' bases in sync
        s0b *= stepB;
        p ^= 1;         // next tile writes the other buffer (no trailing barrier)
    }
#undef ISSUE

#pragma unroll
    for (int f = 0; f < 2; ++f)
#pragma unroll
        for (int r = 0; r < 4; ++r) {
#pragma unroll
            for (int sh = 1; sh < 16; sh <<= 1)
                lpart[f][r] += __shfl_xor(lpart[f][r], sh);
        }

    const int whichw = wave >> 1;
    const int nfar = L_SEQ - 64 * (t_hi_w - t_lo_w);
    const int b = bh >> 3, h = bh & 7;
#pragma unroll
    for (int f = 0; f < 2; ++f) {
        float inv[4];
#pragma unroll
        for (int r = 0; r < 4; ++r)
            inv[r] = 1.0f / (lpart[f][r] + EM8 * (float)nfar);
#pragma unroll
        for (int t = 0; t < 4; ++t) {
            float F = Ftot[t * 16 + r16] - Fband[whichw][t * 16 + r16];
#pragma unroll
            for (int r = 0; r < 4; ++r) {
                int row = q0 + wave * 32 + f * 16 + g * 4 + r;
                float o = (acc[f][t][r] + EM8 * F) * inv[r];
                Og[((size_t)(b * L_SEQ) + row) * DMODEL + h * DHEAD + t * 16 + r16] = f2b_fast(o);
            }
        }
    }
}

extern "C" void kernel_launch(void* const* d_in, const int* in_sizes, int n_in,
                              void* d_out, int out_size, void* d_ws, size_t ws_size,
                              hipStream_t stream) {
    const float* x  = (const float*)d_in[0];
    const float* Wq = (const float*)d_in[1];
    const float* bq = (const float*)d_in[2];
    const float* Wk = (const float*)d_in[3];
    const float* bk = (const float*)d_in[4];
    const float* Wv = (const float*)d_in[5];
    const float* bv = (const float*)d_in[6];
    const float* Wo = (const float*)d_in[7];
    const float* bo = (const float*)d_in[8];
    float* out = (float*)d_out;

    const int NX = MROWS * DMODEL;
    const int NW = DMODEL * DMODEL;

    unsigned short* aout = (unsigned short*)d_ws;  // attn output (bf16)
    unsigned short* wqb = aout + NX;
    unsigned short* wkb = wqb + NW;
    unsigned short* wvb = wkb + NW;
    unsigned short* wob = wvb + NW;
    unsigned short* qws = wob + NW;
    unsigned short* kws = qws + NX;
    unsigned short* vtg = kws + NX;                // V transposed [B,H,Hd,L]
    float* TS = (float*)(vtg + NX);

    cast_w<<<(4 * NW / 4) / 256, 256, 0, stream>>>(Wq, Wk, Wv, Wo, wqb, wkb, wvb, wob);

    dim3 gq(MROWS / 128, DMODEL / 64);
    gemm_qkv<<<gq, 256, 0, stream>>>(x, wqb, wkb, wvb, bq, bk, bv, qws, kws, vtg, TS);

    dim3 ga(L_SEQ / 128, NB * NH);
    attn_fused<<<ga, 256, 0, stream>>>(qws, kws, vtg, TS, aout);

    dim3 go(MROWS / 64, DMODEL / 64);
    gemm_out<<<go, 256, 0, stream>>>(aout, wob, bo, out);
}